// Round 3
// baseline (232.610 us; speedup 1.0000x reference)
//
#include <hip/hip_runtime.h>
#include <hip/hip_bf16.h>
#include <math.h>

#define LATENT 16
#define NREP 10
#define NSTEPS 10
#define NTERMS 169          // 1 + 16 + 136 + 16
#define NCHUNK 12           // 12 x K=16 = 192 k-slots
#define DT 0.01f
#define WS_A_BYTES (NREP * NCHUNK * 64 * 16)   // 122880

typedef __attribute__((ext_vector_type(8))) short short8;     // 8 bf16 (4 VGPRs)
typedef __attribute__((ext_vector_type(16))) float f32x16;    // MFMA 32x32 acc

union Frag8 { short8 v; __hip_bfloat16 e[8]; };

// ---------------- k-axis slot assignment (sigma = XOR-1 pairing) ----------------
// Pair-slot m = c*8 + j, m in [0,96). k-slot = c*16 + hi*8 + j.
// hi=0 lane computes the base term; hi=1 lane computes sigma(term) via hp[] remap.
// types: 0 ONE(hi=1 dead), 1 LIN pair, 2 QUAD pair, 3 SIN pair, 4 FIXQUAD(hi=1 dead), 5 PAD
struct Slot { int type; int a; int b; };

__host__ __device__ constexpr Slot slot_of(int m) {
    if (m == 0)  return Slot{0, 0, 0};
    if (m < 9)   return Slot{1, 2 * (m - 1), 0};
    if (m < 17)  return Slot{3, 2 * (m - 9), 0};
    if (m < 25)  { int a = 2 * (m - 17); return Slot{4, a, a + 1}; }
    if (m < 89) {
        int q = m - 25;
        int t = 0;
        while (q >= 15 - 2 * t) { q -= 15 - 2 * t; ++t; }   // run for a=2t has 15-2t reps
        int a = 2 * t;
        int b = (q == 0) ? a : (a + 1 + q);                 // b = a, then a+2..15 (skip fixed a+1)
        return Slot{2, a, b};
    }
    return Slot{5, 0, 0};
}

__host__ __device__ constexpr int triu_idx(int a, int b) {
    return a * 16 - a * (a - 1) / 2 + (b - a);
}

// library row for k-slot (c,hi,j); -1 = dead (A coefficient forced 0)
__host__ __device__ constexpr int krow_of(int c, int hi, int j) {
    Slot s = slot_of(c * 8 + j);
    switch (s.type) {
        case 0: return hi ? -1 : 0;
        case 1: return 1 + (s.a ^ hi);
        case 3: return 153 + (s.a ^ hi);
        case 4: return hi ? -1 : 17 + triu_idx(s.a, s.b);
        case 2: {
            int a = s.a ^ hi, b = s.b ^ hi;
            if (a > b) { int t2 = a; a = b; b = t2; }
            return 17 + triu_idx(a, b);
        }
        default: return -1;
    }
}

// ---------------- uniform per-step B build (no divergence) ----------------
template<int M>
__device__ __forceinline__ float slot_val(const float (&hp)[LATENT]) {
    constexpr Slot s = slot_of(M);
    if constexpr (s.type == 0) return 1.0f;
    else if constexpr (s.type == 1) return hp[s.a];
    else if constexpr (s.type == 2 || s.type == 4) return hp[s.a] * hp[s.b];
    else if constexpr (s.type == 3) return __sinf(hp[s.a]);
    else return 0.0f;
}

template<int C>
__device__ __forceinline__ short8 build_chunk(const float (&hp)[LATENT]) {
    Frag8 b;
    b.e[0] = __float2bfloat16(slot_val<C * 8 + 0>(hp));
    b.e[1] = __float2bfloat16(slot_val<C * 8 + 1>(hp));
    b.e[2] = __float2bfloat16(slot_val<C * 8 + 2>(hp));
    b.e[3] = __float2bfloat16(slot_val<C * 8 + 3>(hp));
    b.e[4] = __float2bfloat16(slot_val<C * 8 + 4>(hp));
    b.e[5] = __float2bfloat16(slot_val<C * 8 + 5>(hp));
    b.e[6] = __float2bfloat16(slot_val<C * 8 + 6>(hp));
    b.e[7] = __float2bfloat16(slot_val<C * 8 + 7>(hp));
    return b.v;
}

// ---------------- kernel 1: pack A fragments into ws ----------------
// ws layout: short8 wsA[(r*NCHUNK + c)*64 + lane]  (bf16, mask & DT folded, k-mapped)
__global__ __launch_bounds__(768) void pack_A_kernel(
    const float* __restrict__ coeff, const float* __restrict__ mask, int4* __restrict__ wsA)
{
    const int r = blockIdx.x;
    const int c = threadIdx.x >> 6;
    const int lane = threadIdx.x & 63;
    const int col = lane & 31, hi = lane >> 5;
    const float* cr = coeff + (size_t)r * NTERMS * LATENT;
    const float* mr = mask  + (size_t)r * NTERMS * LATENT;
    Frag8 a;
    for (int j = 0; j < 8; ++j) {
        const int row = krow_of(c, hi, j);
        float v = 0.0f;
        if (row >= 0 && col < LATENT) {
            const int idx = row * LATENT + col;
            v = cr[idx] * mr[idx] * DT;
        }
        a.e[j] = __float2bfloat16(v);
    }
    union { short8 s; int4 i; } u; u.s = a.v;
    wsA[((size_t)r * NCHUNK + c) * 64 + lane] = u.i;
}

// ---------------- kernel 2: main integration ----------------
template<bool USE_WS>
__global__ __launch_bounds__(256) void sindy_mfma_kernel(
    const float* __restrict__ h_t,    // [N, 16]
    const float* __restrict__ coeff,  // [10, 169, 16]
    const float* __restrict__ mask,   // [10, 169, 16]
    const int4* __restrict__ wsA,
    float* __restrict__ out,          // [N, 10, 16]
    int N, int ntiles)
{
    const int lane = threadIdx.x & 63;
    const int wid  = blockIdx.x * 4 + (threadIdx.x >> 6);
    if (wid >= NREP * ntiles) return;
    const int r    = wid / ntiles;
    const int tile = wid % ntiles;

    const int col = lane & 31;        // trajectory within tile; also A-row (dim)
    const int hi  = lane >> 5;        // k-slot half
    const bool hb = (hi != 0);

    // ---- A fragments ----
    short8 af[NCHUNK];
    if constexpr (USE_WS) {
        const short8* wa = reinterpret_cast<const short8*>(wsA);
        #pragma unroll
        for (int c = 0; c < NCHUNK; ++c)
            af[c] = wa[((size_t)r * NCHUNK + c) * 64 + lane];
    } else {
        const float* cr = coeff + (size_t)r * NTERMS * LATENT;
        const float* mr = mask  + (size_t)r * NTERMS * LATENT;
        #pragma unroll
        for (int c = 0; c < NCHUNK; ++c) {
            Frag8 a;
            #pragma unroll
            for (int j = 0; j < 8; ++j) {
                const int row = krow_of(c, hi, j);
                float v = 0.0f;
                if (row >= 0 && col < LATENT) {
                    const int idx = row * LATENT + col;
                    v = cr[idx] * mr[idx] * DT;
                }
                a.e[j] = __float2bfloat16(v);
            }
            af[c] = a.v;
        }
    }

    // ---- h for my trajectory (replicated in both hi-lanes) ----
    const int n = tile * 32 + col;
    float h[LATENT];
    if (n < N) {
        const float4* hpnt = reinterpret_cast<const float4*>(h_t + (size_t)n * LATENT);
        float4 q0 = hpnt[0], q1 = hpnt[1], q2 = hpnt[2], q3 = hpnt[3];
        h[0]=q0.x;  h[1]=q0.y;  h[2]=q0.z;  h[3]=q0.w;
        h[4]=q1.x;  h[5]=q1.y;  h[6]=q1.z;  h[7]=q1.w;
        h[8]=q2.x;  h[9]=q2.y;  h[10]=q2.z; h[11]=q2.w;
        h[12]=q3.x; h[13]=q3.y; h[14]=q3.z; h[15]=q3.w;
    } else {
        #pragma unroll
        for (int d = 0; d < LATENT; ++d) h[d] = 0.0f;
    }

    // ---- 10 sequential Euler steps, fully uniform (no wave divergence) ----
    for (int s = 0; s < NSTEPS; ++s) {
        // hp[i] = h[i ^ hi] : 16 cndmask
        float hp[LATENT];
        #pragma unroll
        for (int i = 0; i < LATENT; ++i) hp[i] = hb ? h[i ^ 1] : h[i];

        // acc preload: reg t<8 holds row (t&3)+8*(t>>2)+4*hi -> preload with h so
        // post-MFMA acc = h_new for owned dims. rows 16-31 (regs 8-15) are A-zero pad.
        f32x16 acc;
        #pragma unroll
        for (int t = 0; t < 8; ++t) {
            const int base = (t & 3) + 8 * (t >> 2);
            acc[t] = hb ? h[base + 4] : h[base];
        }
        #pragma unroll
        for (int t = 8; t < 16; ++t) acc[t] = 0.0f;

        #define STEP_CHUNK(C) \
            acc = __builtin_amdgcn_mfma_f32_32x32x16_bf16(af[C], build_chunk<C>(hp), acc, 0, 0, 0);
        STEP_CHUNK(0)  STEP_CHUNK(1)  STEP_CHUNK(2)  STEP_CHUNK(3)
        STEP_CHUNK(4)  STEP_CHUNK(5)  STEP_CHUNK(6)  STEP_CHUNK(7)
        STEP_CHUNK(8)  STEP_CHUNK(9)  STEP_CHUNK(10) STEP_CHUNK(11)
        #undef STEP_CHUNK

        // cross the hi-halves and commit h_new: 8 shfl + 16 cndmask
        float p[8];
        #pragma unroll
        for (int t = 0; t < 8; ++t) p[t] = __shfl_xor(acc[t], 32);

        #pragma unroll
        for (int d = 0; d < LATENT; ++d) {
            const int t = (d & 3) + 4 * (d >> 3);
            const bool own = ((((d >> 2) & 1) != 0) == hb);
            h[d] = own ? acc[t] : p[t];
        }
    }

    // ---- store out[n][r][:]: each half writes two float4 quarters ----
    if (n < N) {
        float* op = out + ((size_t)n * NREP + r) * LATENT;
        if (!hb) {
            *reinterpret_cast<float4*>(op + 0) = make_float4(h[0], h[1], h[2], h[3]);
            *reinterpret_cast<float4*>(op + 8) = make_float4(h[8], h[9], h[10], h[11]);
        } else {
            *reinterpret_cast<float4*>(op + 4)  = make_float4(h[4], h[5], h[6], h[7]);
            *reinterpret_cast<float4*>(op + 12) = make_float4(h[12], h[13], h[14], h[15]);
        }
    }
}

extern "C" void kernel_launch(void* const* d_in, const int* in_sizes, int n_in,
                              void* d_out, int out_size, void* d_ws, size_t ws_size,
                              hipStream_t stream) {
    const float* h_t   = (const float*)d_in[0];
    const float* coeff = (const float*)d_in[1];
    const float* mask  = (const float*)d_in[2];
    float* out = (float*)d_out;

    const int N = in_sizes[0] / LATENT;          // 50000
    const int ntiles = (N + 31) / 32;            // 1563
    const int nwaves = NREP * ntiles;            // 15630
    const int nblocks = (nwaves + 3) / 4;

    if (ws_size >= (size_t)WS_A_BYTES) {
        int4* wsA = (int4*)d_ws;
        pack_A_kernel<<<dim3(NREP), dim3(768), 0, stream>>>(coeff, mask, wsA);
        sindy_mfma_kernel<true><<<dim3(nblocks), dim3(256), 0, stream>>>(
            h_t, coeff, mask, wsA, out, N, ntiles);
    } else {
        sindy_mfma_kernel<false><<<dim3(nblocks), dim3(256), 0, stream>>>(
            h_t, coeff, mask, (const int4*)d_ws, out, N, ntiles);
    }
}

// Round 4
// 102.892 us; speedup vs baseline: 2.2607x; 2.2607x over previous
//
#include <hip/hip_runtime.h>
#include <hip/hip_bf16.h>
#include <math.h>

#define LATENT 16
#define NREP 10
#define NSTEPS 10
#define NTERMS 169          // 1 + 16 + 136 + 16
#define NCHUNK 12           // 12 x K=16 = 192 k-slots
#define DT 0.01f
#define WS_A_BYTES (NREP * NCHUNK * 64 * 16)   // 122880

typedef __attribute__((ext_vector_type(8))) short short8;     // 8 bf16 (4 VGPRs)
typedef __attribute__((ext_vector_type(16))) float f32x16;    // MFMA 32x32 acc

union Frag8 { short8 v; __hip_bfloat16 e[8]; };

// ---------------- k-axis slot assignment (sigma = XOR-1 pairing) ----------------
// Pair-slot m = c*8 + j, m in [0,96). k-slot = c*16 + hi*8 + j.
// hi=0 lanes compute base terms on hl(=h); hi=1 lanes run the SAME slot program on
// hl(=sigma(h)), yielding the sigma-paired term. Verified by round-2/3 passes.
// types: 0 ONE(hi=1 dead), 1 LIN pair, 2 QUAD pair, 3 SIN pair, 4 FIXQUAD(hi=1 dead), 5 PAD
struct Slot { int type; int a; int b; };

__host__ __device__ constexpr Slot slot_of(int m) {
    if (m == 0)  return Slot{0, 0, 0};
    if (m < 9)   return Slot{1, 2 * (m - 1), 0};
    if (m < 17)  return Slot{3, 2 * (m - 9), 0};
    if (m < 25)  { int a = 2 * (m - 17); return Slot{4, a, a + 1}; }
    if (m < 89) {
        int q = m - 25;
        int t = 0;
        while (q >= 15 - 2 * t) { q -= 15 - 2 * t; ++t; }
        int a = 2 * t;
        int b = (q == 0) ? a : (a + 1 + q);
        return Slot{2, a, b};
    }
    return Slot{5, 0, 0};
}

__host__ __device__ constexpr int triu_idx(int a, int b) {
    return a * 16 - a * (a - 1) / 2 + (b - a);
}

// library row for k-slot (c,hi,j); -1 = dead (A coefficient forced 0)
__host__ __device__ constexpr int krow_of(int c, int hi, int j) {
    Slot s = slot_of(c * 8 + j);
    switch (s.type) {
        case 0: return hi ? -1 : 0;
        case 1: return 1 + (s.a ^ hi);
        case 3: return 153 + (s.a ^ hi);
        case 4: return hi ? -1 : 17 + triu_idx(s.a, s.b);
        case 2: {
            int a = s.a ^ hi, b = s.b ^ hi;
            if (a > b) { int t2 = a; a = b; b = t2; }
            return 17 + triu_idx(a, b);
        }
        default: return -1;
    }
}

// A-matrix row -> output dim. Rows 0-15: dim=row. Rows 16-31: dim=(row&15)^4.
// The duplicate rows make every lane's 16 acc regs cover all 16 dims (no shuffle).
__host__ __device__ constexpr int dim_of_arow(int row) {
    return (row < 16) ? row : ((row & 15) ^ 4);
}

// ---------------- uniform per-step B build (no divergence) ----------------
template<int M>
__device__ __forceinline__ float slot_val(const float (&hl)[LATENT]) {
    constexpr Slot s = slot_of(M);
    if constexpr (s.type == 0) return 1.0f;
    else if constexpr (s.type == 1) return hl[s.a];
    else if constexpr (s.type == 2 || s.type == 4) return hl[s.a] * hl[s.b];
    else if constexpr (s.type == 3) return __sinf(hl[s.a]);
    else return 0.0f;
}

template<int C>
__device__ __forceinline__ short8 build_chunk(const float (&hl)[LATENT]) {
    Frag8 b;
    b.e[0] = __float2bfloat16(slot_val<C * 8 + 0>(hl));
    b.e[1] = __float2bfloat16(slot_val<C * 8 + 1>(hl));
    b.e[2] = __float2bfloat16(slot_val<C * 8 + 2>(hl));
    b.e[3] = __float2bfloat16(slot_val<C * 8 + 3>(hl));
    b.e[4] = __float2bfloat16(slot_val<C * 8 + 4>(hl));
    b.e[5] = __float2bfloat16(slot_val<C * 8 + 5>(hl));
    b.e[6] = __float2bfloat16(slot_val<C * 8 + 6>(hl));
    b.e[7] = __float2bfloat16(slot_val<C * 8 + 7>(hl));
    return b.v;
}

// ---------------- kernel 1: pack A fragments into ws ----------------
// ws layout: short8 wsA[(r*NCHUNK + c)*64 + lane]  (bf16, mask & DT folded, k-mapped,
// rows 16-31 duplicated per dim_of_arow)
__global__ __launch_bounds__(768) void pack_A_kernel(
    const float* __restrict__ coeff, const float* __restrict__ mask, int4* __restrict__ wsA)
{
    const int r = blockIdx.x;
    const int c = threadIdx.x >> 6;
    const int lane = threadIdx.x & 63;
    const int col = lane & 31, hi = lane >> 5;
    const int dim = dim_of_arow(col);
    const float* cr = coeff + (size_t)r * NTERMS * LATENT;
    const float* mr = mask  + (size_t)r * NTERMS * LATENT;
    Frag8 a;
    for (int j = 0; j < 8; ++j) {
        const int row = krow_of(c, hi, j);
        float v = 0.0f;
        if (row >= 0) {
            const int idx = row * LATENT + dim;
            v = cr[idx] * mr[idx] * DT;
        }
        a.e[j] = __float2bfloat16(v);
    }
    union { short8 s; int4 i; } u; u.s = a.v;
    wsA[((size_t)r * NCHUNK + c) * 64 + lane] = u.i;
}

// ---------------- kernel 2: main integration ----------------
template<bool USE_WS>
__global__ __launch_bounds__(256, 4) void sindy_mfma_kernel(
    const float* __restrict__ h_t,    // [N, 16]
    const float* __restrict__ coeff,  // [10, 169, 16]
    const float* __restrict__ mask,   // [10, 169, 16]
    const int4* __restrict__ wsA,
    float* __restrict__ out,          // [N, 10, 16]
    int N, int ntiles)
{
    const int lane = threadIdx.x & 63;
    const int wid  = blockIdx.x * 4 + (threadIdx.x >> 6);
    if (wid >= NREP * ntiles) return;
    const int r    = wid / ntiles;
    const int tile = wid % ntiles;

    const int col = lane & 31;        // trajectory within tile; also A-row
    const bool hb = (lane >> 5) != 0; // k-slot half

    // ---- A fragments (48 VGPR, live across the step loop) ----
    short8 af[NCHUNK];
    if constexpr (USE_WS) {
        const short8* wa = reinterpret_cast<const short8*>(wsA);
        #pragma unroll
        for (int c = 0; c < NCHUNK; ++c)
            af[c] = wa[((size_t)r * NCHUNK + c) * 64 + lane];
    } else {
        const int hi = hb ? 1 : 0;
        const int dim = dim_of_arow(col);
        const float* cr = coeff + (size_t)r * NTERMS * LATENT;
        const float* mr = mask  + (size_t)r * NTERMS * LATENT;
        #pragma unroll
        for (int c = 0; c < NCHUNK; ++c) {
            Frag8 a;
            #pragma unroll
            for (int j = 0; j < 8; ++j) {
                const int row = krow_of(c, hi, j);
                float v = 0.0f;
                if (row >= 0) {
                    const int idx = row * LATENT + dim;
                    v = cr[idx] * mr[idx] * DT;
                }
                a.e[j] = __float2bfloat16(v);
            }
            af[c] = a.v;
        }
    }

    // ---- h for my trajectory, stored PERMUTED: hl[i] = h[i ^ hi] ----
    const int n = tile * 32 + col;
    float hl[LATENT];
    {
        float h[LATENT];
        if (n < N) {
            const float4* hp4 = reinterpret_cast<const float4*>(h_t + (size_t)n * LATENT);
            float4 q0 = hp4[0], q1 = hp4[1], q2 = hp4[2], q3 = hp4[3];
            h[0]=q0.x;  h[1]=q0.y;  h[2]=q0.z;  h[3]=q0.w;
            h[4]=q1.x;  h[5]=q1.y;  h[6]=q1.z;  h[7]=q1.w;
            h[8]=q2.x;  h[9]=q2.y;  h[10]=q2.z; h[11]=q2.w;
            h[12]=q3.x; h[13]=q3.y; h[14]=q3.z; h[15]=q3.w;
        } else {
            #pragma unroll
            for (int d = 0; d < LATENT; ++d) h[d] = 0.0f;
        }
        #pragma unroll
        for (int i = 0; i < LATENT; ++i) hl[i] = hb ? h[i ^ 1] : h[i];
    }

    // ---- 10 sequential Euler steps, uniform, shuffle-free ----
    for (int s = 0; s < NSTEPS; ++s) {
        // Preload acc[t] = h[dim(t,hi)] = hl[dim(t,hi)^hi] so post-MFMA acc = h_new.
        f32x16 acc;
        #pragma unroll
        for (int t = 0; t < 8; ++t) {
            const int i0 = (t & 3) + 8 * (t >> 2);              // hi=0
            const int i1 = ((t & 3) ^ 1) + 8 * (t >> 2) + 4;    // hi=1
            acc[t] = hb ? hl[i1] : hl[i0];
        }
        #pragma unroll
        for (int t = 8; t < 16; ++t) {
            const int i0 = (t & 3) + 8 * ((t >> 2) & 1) + 4;    // hi=0
            const int i1 = ((t & 3) ^ 1) + 8 * ((t >> 2) & 1);  // hi=1
            acc[t] = hb ? hl[i1] : hl[i0];
        }

        #define STEP_CHUNK(C) \
            acc = __builtin_amdgcn_mfma_f32_32x32x16_bf16(af[C], build_chunk<C>(hl), acc, 0, 0, 0);
        STEP_CHUNK(0)  STEP_CHUNK(1)  STEP_CHUNK(2)  STEP_CHUNK(3)
        STEP_CHUNK(4)  STEP_CHUNK(5)  STEP_CHUNK(6)  STEP_CHUNK(7)
        STEP_CHUNK(8)  STEP_CHUNK(9)  STEP_CHUNK(10) STEP_CHUNK(11)
        #undef STEP_CHUNK

        // Commit: hl[i] = h_new[i^hi]; acc reg chosen compile-time per half.
        #pragma unroll
        for (int i = 0; i < LATENT; ++i) {
            const int b2 = (i >> 2) & 1;
            const int t0 = (b2 == 0) ? ((i & 3) + 4 * (i >> 3))
                                     : (8 + (i & 3) + 4 * (i >> 3));         // hi=0
            const int t1 = (b2 == 1) ? (((i & 3) ^ 1) + 4 * (i >> 3))
                                     : (8 + ((i & 3) ^ 1) + 4 * (i >> 3));   // hi=1
            hl[i] = hb ? acc[t1] : acc[t0];
        }
    }

    // ---- store out[n][r][:]: h[d] = hl[d^hi]; each half writes 2 float4 ----
    if (n < N) {
        float* op = out + ((size_t)n * NREP + r) * LATENT;
        if (!hb) {
            *reinterpret_cast<float4*>(op + 0) = make_float4(hl[0], hl[1], hl[2], hl[3]);
            *reinterpret_cast<float4*>(op + 8) = make_float4(hl[8], hl[9], hl[10], hl[11]);
        } else {
            *reinterpret_cast<float4*>(op + 4)  = make_float4(hl[5], hl[4], hl[7], hl[6]);
            *reinterpret_cast<float4*>(op + 12) = make_float4(hl[13], hl[12], hl[15], hl[14]);
        }
    }
}

extern "C" void kernel_launch(void* const* d_in, const int* in_sizes, int n_in,
                              void* d_out, int out_size, void* d_ws, size_t ws_size,
                              hipStream_t stream) {
    const float* h_t   = (const float*)d_in[0];
    const float* coeff = (const float*)d_in[1];
    const float* mask  = (const float*)d_in[2];
    float* out = (float*)d_out;

    const int N = in_sizes[0] / LATENT;          // 50000
    const int ntiles = (N + 31) / 32;            // 1563
    const int nwaves = NREP * ntiles;            // 15630
    const int nblocks = (nwaves + 3) / 4;

    if (ws_size >= (size_t)WS_A_BYTES) {
        int4* wsA = (int4*)d_ws;
        pack_A_kernel<<<dim3(NREP), dim3(768), 0, stream>>>(coeff, mask, wsA);
        sindy_mfma_kernel<true><<<dim3(nblocks), dim3(256), 0, stream>>>(
            h_t, coeff, mask, wsA, out, N, ntiles);
    } else {
        sindy_mfma_kernel<false><<<dim3(nblocks), dim3(256), 0, stream>>>(
            h_t, coeff, mask, (const int4*)d_ws, out, N, ntiles);
    }
}

// Round 5
// 80.362 us; speedup vs baseline: 2.8945x; 1.2804x over previous
//
#include <hip/hip_runtime.h>
#include <hip/hip_bf16.h>
#include <math.h>

#define LATENT 16
#define NREP 10
#define NSTEPS 10
#define NTERMS 169          // 1 + 16 + 136 + 16
#define NCHUNK 6            // 6 x K=32 = 192 k-slots (168 live + 24 dead, ONE folded)
#define DT 0.01f

#define WS_A_BYTES (NREP * NCHUNK * 64 * 16)     // 61440
#define WS_C0_OFF  WS_A_BYTES
#define WS_TOTAL   (WS_A_BYTES + NREP * LATENT * 4)

typedef __attribute__((ext_vector_type(8))) short short8;   // 8 bf16 (4 VGPRs)
typedef __attribute__((ext_vector_type(4))) float f32x4;    // MFMA 16x16 acc

union Frag8 { short8 v; __hip_bfloat16 e[8]; };

// ---------------- base-slot program (48 slots, shared by all 4 k-groups) ------
// Lane group g holds hl[i] = h[i ^ 4g]; running the SAME slot program on hl
// yields the sigma_g-image term. sigma_g = XOR(4g) acts on dim high-bits.
// Slots: 0-3 LIN(a), 4-7 SIN(a), 8-11 DIAG (a,a), 12-23 size-2 quad orbits
// (a, a+4t), 24-29 type-A quad (alpha,beta in block0), 30-47 type-B quad
// (alpha, beta+hb). Orbit coverage: 16 lin + 16 sin + 16 diag + 24 + 96 = 168
// rows; ONE (row 0) folded into the acc preload constant c0.
struct Slot { int type; int a; int b; };  // 0 LIN, 1 SIN, 2 QUAD

__host__ __device__ constexpr Slot slot_of(int m) {
    if (m < 4)  return Slot{0, m, 0};
    if (m < 8)  return Slot{1, m - 4, 0};
    if (m < 12) return Slot{2, m - 8, m - 8};
    if (m < 24) { int a = (m - 12) / 3, t = (m - 12) % 3 + 1; return Slot{2, a, a + 4 * t}; }
    int idx = (m < 30) ? (m - 24) : (m - 30);
    int p   = (m < 30) ? idx : idx / 3;
    int hb  = (m < 30) ? 0 : 4 * (idx % 3 + 1);
    int x = (p < 3) ? 0 : (p < 5 ? 1 : 2);
    int y = (p < 3) ? (p + 1) : (p < 5 ? (p - 1) : 3);
    return Slot{2, x, y + hb};
}

// library row for (base-slot m, group g); -1 = dead (A coefficient forced 0)
__host__ __device__ constexpr int krow_of(int m, int g) {
    Slot s = slot_of(m);
    const int sh = 4 * g;
    if (s.type == 0) return 1 + (s.a ^ sh);
    if (s.type == 1) return 153 + (s.a ^ sh);
    if (m >= 12 && m < 24) {   // size-2 orbits: half the groups duplicate
        const int t = (m - 12) % 3 + 1;
        const bool live = (t == 1) ? (g == 0 || g == 2) : (g == 0 || g == 1);
        if (!live) return -1;
    }
    int x = s.a ^ sh, y = s.b ^ sh;
    if (x > y) { int tmp = x; x = y; y = tmp; }
    return 17 + x * 16 - x * (x - 1) / 2 + (y - x);   // np.triu_indices order
}

// ---------------- uniform per-step B build ----------------
template<int M>
__device__ __forceinline__ float slot_val(const float (&hl)[LATENT]) {
    constexpr Slot s = slot_of(M);
    if constexpr (s.type == 0) return hl[s.a];
    else if constexpr (s.type == 1) return __sinf(hl[s.a]);
    else return hl[s.a] * hl[s.b];
}

template<int C>
__device__ __forceinline__ short8 build_chunk(const float (&hl)[LATENT]) {
    Frag8 b;
    b.e[0] = __float2bfloat16(slot_val<C * 8 + 0>(hl));
    b.e[1] = __float2bfloat16(slot_val<C * 8 + 1>(hl));
    b.e[2] = __float2bfloat16(slot_val<C * 8 + 2>(hl));
    b.e[3] = __float2bfloat16(slot_val<C * 8 + 3>(hl));
    b.e[4] = __float2bfloat16(slot_val<C * 8 + 4>(hl));
    b.e[5] = __float2bfloat16(slot_val<C * 8 + 5>(hl));
    b.e[6] = __float2bfloat16(slot_val<C * 8 + 6>(hl));
    b.e[7] = __float2bfloat16(slot_val<C * 8 + 7>(hl));
    return b.v;
}

// ---------------- kernel 1: pack A fragments + c0 into ws ----------------
// wsA: int4 [(r*NCHUNK + c)*64 + lane]; lane: d=lane&15, g=lane>>4,
// elem e -> row krow_of(c*8+e, g), column d, masked * DT, bf16.
// wsC0: float [r*16 + dim] = coeff[r][0][dim]*mask*DT.
__global__ __launch_bounds__(384) void pack_A16_kernel(
    const float* __restrict__ coeff, const float* __restrict__ mask, char* __restrict__ ws)
{
    const int r = blockIdx.x;
    const int tid = threadIdx.x;          // 384 = 6 chunks x 64 lanes
    const int c = tid >> 6, lane = tid & 63;
    const int d = lane & 15, g = lane >> 4;
    const float* cr = coeff + (size_t)r * NTERMS * LATENT;
    const float* mr = mask  + (size_t)r * NTERMS * LATENT;
    Frag8 a;
    for (int e = 0; e < 8; ++e) {
        const int row = krow_of(c * 8 + e, g);
        float v = 0.0f;
        if (row >= 0) v = cr[row * LATENT + d] * mr[row * LATENT + d] * DT;
        a.e[e] = __float2bfloat16(v);
    }
    union { short8 s; int4 i; } u; u.s = a.v;
    reinterpret_cast<int4*>(ws)[((size_t)r * NCHUNK + c) * 64 + lane] = u.i;

    if (tid < LATENT) {
        float* c0p = reinterpret_cast<float*>(ws + WS_C0_OFF);
        c0p[r * LATENT + tid] = cr[tid] * mr[tid] * DT;   // library row 0
    }
}

// ---------------- kernel 2: main integration ----------------
// One wave = 16 trajectories x 4 k-groups. col=lane&15 (D col & A row-dim base),
// g=lane>>4. hl permanently sigma_g-permuted; update via 12 shfl_xor, no cndmask.
template<bool USE_WS>
__global__ __launch_bounds__(256, 4) void sindy_mfma16_kernel(
    const float* __restrict__ h_t,    // [N, 16]
    const float* __restrict__ coeff,  // [10, 169, 16]
    const float* __restrict__ mask,   // [10, 169, 16]
    const char* __restrict__ ws,
    float* __restrict__ out,          // [N, 10, 16]
    int N, int ntiles)
{
    const int lane = threadIdx.x & 63;
    const int wid  = blockIdx.x * 4 + (threadIdx.x >> 6);
    if (wid >= NREP * ntiles) return;
    const int r    = wid / ntiles;
    const int tile = wid % ntiles;

    const int col = lane & 15;        // trajectory within tile
    const int g   = lane >> 4;        // k-group; sigma = XOR(4g)

    // ---- A fragments (24 VGPR, loop-invariant) ----
    short8 af[NCHUNK];
    if constexpr (USE_WS) {
        const short8* wa = reinterpret_cast<const short8*>(ws);
        #pragma unroll
        for (int c = 0; c < NCHUNK; ++c)
            af[c] = wa[((size_t)r * NCHUNK + c) * 64 + lane];
    } else {
        const float* cr = coeff + (size_t)r * NTERMS * LATENT;
        const float* mr = mask  + (size_t)r * NTERMS * LATENT;
        #pragma unroll
        for (int c = 0; c < NCHUNK; ++c) {
            Frag8 a;
            #pragma unroll
            for (int e = 0; e < 8; ++e) {
                const int row = krow_of(c * 8 + e, g);
                float v = 0.0f;
                if (row >= 0) v = cr[row * LATENT + col] * mr[row * LATENT + col] * DT;
                a.e[e] = __float2bfloat16(v);
            }
            af[c] = a.v;
        }
    }

    // ---- constant column (ONE term), per-lane dims 4g..4g+3 ----
    float c0[4];
    if constexpr (USE_WS) {
        const float4 v = *reinterpret_cast<const float4*>(
            ws + WS_C0_OFF + ((size_t)r * LATENT + 4 * g) * 4);
        c0[0] = v.x; c0[1] = v.y; c0[2] = v.z; c0[3] = v.w;
    } else {
        const float* cr = coeff + (size_t)r * NTERMS * LATENT;
        const float* mr = mask  + (size_t)r * NTERMS * LATENT;
        #pragma unroll
        for (int j = 0; j < 4; ++j) {
            const int d2 = 4 * g + j;
            c0[j] = cr[d2] * mr[d2] * DT;
        }
    }

    // ---- h, stored permuted: hl[4u+j] = h[4(u^g)+j] (memory-offset permute) ----
    const int n = tile * 16 + col;
    float hl[LATENT];
    if (n < N) {
        const float* hp = h_t + (size_t)n * LATENT;
        #pragma unroll
        for (int u = 0; u < 4; ++u) {
            const float4 q = *reinterpret_cast<const float4*>(hp + 4 * (u ^ g));
            hl[4 * u + 0] = q.x; hl[4 * u + 1] = q.y;
            hl[4 * u + 2] = q.z; hl[4 * u + 3] = q.w;
        }
    } else {
        #pragma unroll
        for (int i = 0; i < LATENT; ++i) hl[i] = 0.0f;
    }

    // ---- 10 sequential Euler steps ----
    for (int s = 0; s < NSTEPS; ++s) {
        // preload: acc[j] = h_old[4g+j] + c0 = hl[j] + c0[j]  (uniform reg index)
        f32x4 acc;
        acc[0] = hl[0] + c0[0]; acc[1] = hl[1] + c0[1];
        acc[2] = hl[2] + c0[2]; acc[3] = hl[3] + c0[3];

        #define STEP_CHUNK(C) \
            acc = __builtin_amdgcn_mfma_f32_16x16x32_bf16(af[C], build_chunk<C>(hl), acc, 0, 0, 0);
        STEP_CHUNK(0) STEP_CHUNK(1) STEP_CHUNK(2)
        STEP_CHUNK(3) STEP_CHUNK(4) STEP_CHUNK(5)
        #undef STEP_CHUNK

        // update: acc[j] = h_new[4g+j]; hl_new[4q+j] = shfl_xor(acc[j], 16q)
        hl[0] = acc[0]; hl[1] = acc[1]; hl[2] = acc[2]; hl[3] = acc[3];
        #pragma unroll
        for (int j = 0; j < 4; ++j) {
            hl[4 + j]  = __shfl_xor(acc[j], 16);
            hl[8 + j]  = __shfl_xor(acc[j], 32);
            hl[12 + j] = __shfl_xor(acc[j], 48);
        }
    }

    // ---- store: out[n][r][4g+j] = h[4g+j] = hl[j] ----
    if (n < N) {
        float* op = out + ((size_t)n * NREP + r) * LATENT + 4 * g;
        *reinterpret_cast<float4*>(op) = make_float4(hl[0], hl[1], hl[2], hl[3]);
    }
}

extern "C" void kernel_launch(void* const* d_in, const int* in_sizes, int n_in,
                              void* d_out, int out_size, void* d_ws, size_t ws_size,
                              hipStream_t stream) {
    const float* h_t   = (const float*)d_in[0];
    const float* coeff = (const float*)d_in[1];
    const float* mask  = (const float*)d_in[2];
    float* out = (float*)d_out;

    const int N = in_sizes[0] / LATENT;          // 50000
    const int ntiles = (N + 15) / 16;            // 3125
    const int nwaves = NREP * ntiles;            // 31250
    const int nblocks = (nwaves + 3) / 4;

    if (ws_size >= (size_t)WS_TOTAL) {
        pack_A16_kernel<<<dim3(NREP), dim3(384), 0, stream>>>(coeff, mask, (char*)d_ws);
        sindy_mfma16_kernel<true><<<dim3(nblocks), dim3(256), 0, stream>>>(
            h_t, coeff, mask, (const char*)d_ws, out, N, ntiles);
    } else {
        sindy_mfma16_kernel<false><<<dim3(nblocks), dim3(256), 0, stream>>>(
            h_t, coeff, mask, (const char*)d_ws, out, N, ntiles);
    }
}

// Round 7
// 61.776 us; speedup vs baseline: 3.7654x; 1.3009x over previous
//
#include <hip/hip_runtime.h>
#include <hip/hip_bf16.h>
#include <math.h>

#define LATENT 16
#define NREP 10
#define NSTEPS 10
#define NTERMS 169          // 1 + 16 + 136 + 16
#define NCHUNK 7            // 7 x K=32 = 224 k-slots (168 live + dead pads; ONE folded)
#define DT 0.01f
#define ASCALE 1024.0f      // exact pow2: lifts f16 A-coeffs out of subnormal range
#define INV_ASCALE (1.0f/1024.0f)

#define WS_A_BYTES (NREP * NCHUNK * 64 * 16)     // 71680
#define WS_C0_OFF  WS_A_BYTES
#define WS_TOTAL   (WS_A_BYTES + NREP * LATENT * 4)

typedef _Float16 h2 __attribute__((ext_vector_type(2)));
typedef _Float16 half8 __attribute__((ext_vector_type(8)));
typedef __fp16 fp16x2 __attribute__((ext_vector_type(2)));
typedef __attribute__((ext_vector_type(4))) float f32x4;

union FragH  { half8 v; h2 p[4]; int4 i4; };
union FragHE { half8 v; _Float16 e[8]; int4 i4; };

#define SW(x) __builtin_shufflevector((x), (x), 1, 0)

// v_cvt_pkrtz_f16_f32 with a bit-exact type bridge (__fp16x2 -> _Float16x2)
__device__ __forceinline__ h2 pkrtz(float a, float b) {
    fp16x2 r = __builtin_amdgcn_cvt_pkrtz(a, b);
    return __builtin_bit_cast(h2, r);
}

// ---------------- slot -> library row mapping --------------------------------
// Base program of 56 slots shared by all 4 k-groups g (sigma_g = XOR(4g) on dims,
// = XOR(2g) on pair index u, dim = 2u+b). Lane group g holds hl[i] = h[i^4g] and
// hp[u] = (hl[2u], hl[2u+1]); running the SAME program yields the sigma_g-image.
// Slots: 0-3 LIN(a=0..3), 4-7 SIN(a=0..3), 8-11 DIAG(a=0..3),
// 12-13 within-pair cross (h0h1, h2h3),
// 14-29 odd-distance pair reps {P0,Pv} v=1,3,5,7 (4 products each, all groups live),
// 30-53 even-distance pair reps {0,2},{1,3},{0,4},{1,5},{0,6},{1,7} (half groups dead),
// 54-55 dead pad. ONE (row 0) folded into acc preload.
__host__ __device__ constexpr int quadrow(int x, int y) {
    if (x > y) { int t = x; x = y; y = t; }
    return 17 + x * 16 - x * (x - 1) / 2 + (y - x);     // np.triu_indices order
}

__host__ __device__ constexpr int krow16(int m, int g) {
    const int sh = 4 * g;
    if (m < 4)  return 1 + (m ^ sh);
    if (m < 8)  return 153 + ((m - 4) ^ sh);
    if (m < 12) { const int a = (m - 8) ^ sh; return quadrow(a, a); }
    if (m < 14) { const int u = m - 12; return quadrow((2*u) ^ sh, (2*u+1) ^ sh); }
    if (m < 30) {
        const int idx = m - 14, rep = idx >> 2, w = idx & 3;
        const int v = 2 * rep + 1;                       // pair index v in {1,3,5,7}
        const int a = ((w == 1 || w == 3) ? 1 : 0);      // w0:(0,2v) w1:(1,2v+1) w2:(0,2v+1) w3:(1,2v)
        const int b = 2 * v + ((w == 1 || w == 2) ? 1 : 0);
        return quadrow(a ^ sh, b ^ sh);
    }
    if (m < 54) {
        const int idx = m - 30, rep = idx >> 2, w = idx & 3;
        const int u = rep & 1;                           // reps {0,2},{1,3},{0,4},{1,5},{0,6},{1,7}
        const int v = 2 + 2 * (rep >> 1) + (rep & 1);
        const int d = u ^ v;
        const bool live = (d == 2) ? (g == 0 || g == 2) : (g == 0 || g == 1);
        if (!live) return -1;
        const int a = 2 * u + ((w == 1 || w == 3) ? 1 : 0);
        const int b = 2 * v + ((w == 1 || w == 2) ? 1 : 0);
        return quadrow(a ^ sh, b ^ sh);
    }
    return -1;
}

// ---------------- kernel 1: pack A fragments + c0 into ws ----------------
// wsA: int4 [(r*NCHUNK + c)*64 + lane]; lane: d=lane&15 (dim col), g=lane>>4.
// elem e -> row krow16(c*8+e, g), f16, *mask*DT*ASCALE.
// wsC0: float [r*16 + dim] = coeff[r][0][dim]*mask*DT*ASCALE.
__global__ __launch_bounds__(448) void pack_A16_kernel(
    const float* __restrict__ coeff, const float* __restrict__ mask, char* __restrict__ ws)
{
    const int r = blockIdx.x;
    const int tid = threadIdx.x;          // 448 = 7 chunks x 64 lanes
    const int c = tid >> 6, lane = tid & 63;
    const int d = lane & 15, g = lane >> 4;
    const float* cr = coeff + (size_t)r * NTERMS * LATENT;
    const float* mr = mask  + (size_t)r * NTERMS * LATENT;
    FragHE a;
    for (int e = 0; e < 8; ++e) {
        const int row = krow16(c * 8 + e, g);
        float v = 0.0f;
        if (row >= 0) v = cr[row * LATENT + d] * mr[row * LATENT + d] * (DT * ASCALE);
        a.e[e] = (_Float16)v;
    }
    reinterpret_cast<int4*>(ws)[((size_t)r * NCHUNK + c) * 64 + lane] = a.i4;

    if (tid < LATENT) {
        float* c0p = reinterpret_cast<float*>(ws + WS_C0_OFF);
        c0p[r * LATENT + tid] = cr[tid] * mr[tid] * (DT * ASCALE);   // library row 0
    }
}

// ---------------- kernel 2: main integration ----------------
// One wave = 16 trajectories x 4 k-groups. col=lane&15, g=lane>>4.
// hl permanently sigma_g-permuted (memory-offset permute at load).
template<bool USE_WS>
__global__ __launch_bounds__(256, 4) void sindy_f16_kernel(
    const float* __restrict__ h_t,    // [N, 16]
    const float* __restrict__ coeff,  // [10, 169, 16]
    const float* __restrict__ mask,   // [10, 169, 16]
    const char* __restrict__ ws,
    float* __restrict__ out,          // [N, 10, 16]
    int N, int ntiles)
{
    const int lane = threadIdx.x & 63;
    const int wid  = blockIdx.x * 4 + (threadIdx.x >> 6);
    if (wid >= NREP * ntiles) return;
    const int r    = wid / ntiles;
    const int tile = wid % ntiles;

    const int col = lane & 15;        // trajectory within tile; also A dim column
    const int g   = lane >> 4;        // k-group; sigma = XOR(4g)

    // ---- A fragments (28 VGPR, loop-invariant) ----
    half8 af[NCHUNK];
    if constexpr (USE_WS) {
        const int4* wa = reinterpret_cast<const int4*>(ws);
        #pragma unroll
        for (int c = 0; c < NCHUNK; ++c) {
            FragH a; a.i4 = wa[((size_t)r * NCHUNK + c) * 64 + lane];
            af[c] = a.v;
        }
    } else {
        const float* cr = coeff + (size_t)r * NTERMS * LATENT;
        const float* mr = mask  + (size_t)r * NTERMS * LATENT;
        #pragma unroll
        for (int c = 0; c < NCHUNK; ++c) {
            FragHE a;
            #pragma unroll
            for (int e = 0; e < 8; ++e) {
                const int row = krow16(c * 8 + e, g);
                float v = 0.0f;
                if (row >= 0) v = cr[row * LATENT + col] * mr[row * LATENT + col] * (DT * ASCALE);
                a.e[e] = (_Float16)v;
            }
            af[c] = a.v;
        }
    }

    // ---- scaled constant column (ONE term), dims 4g..4g+3 ----
    float c0s[4];
    if constexpr (USE_WS) {
        const float4 v = *reinterpret_cast<const float4*>(
            ws + WS_C0_OFF + ((size_t)r * LATENT + 4 * g) * 4);
        c0s[0] = v.x; c0s[1] = v.y; c0s[2] = v.z; c0s[3] = v.w;
    } else {
        const float* cr = coeff + (size_t)r * NTERMS * LATENT;
        const float* mr = mask  + (size_t)r * NTERMS * LATENT;
        #pragma unroll
        for (int j = 0; j < 4; ++j) {
            const int d2 = 4 * g + j;
            c0s[j] = cr[d2] * mr[d2] * (DT * ASCALE);
        }
    }

    // ---- h, stored permuted: hl[4u+j] = h[4(u^g)+j] ----
    const int n = tile * 16 + col;
    float hl[LATENT];
    if (n < N) {
        const float* hp_ = h_t + (size_t)n * LATENT;
        #pragma unroll
        for (int u = 0; u < 4; ++u) {
            const float4 q = *reinterpret_cast<const float4*>(hp_ + 4 * (u ^ g));
            hl[4 * u + 0] = q.x; hl[4 * u + 1] = q.y;
            hl[4 * u + 2] = q.z; hl[4 * u + 3] = q.w;
        }
    } else {
        #pragma unroll
        for (int i = 0; i < LATENT; ++i) hl[i] = 0.0f;
    }

    // ---- 10 sequential Euler steps ----
    for (int s = 0; s < NSTEPS; ++s) {
        // f16 pair registers: hp[u] = (hl[2u], hl[2u+1])
        h2 hp[8];
        #pragma unroll
        for (int u = 0; u < 8; ++u)
            hp[u] = pkrtz(hl[2 * u], hl[2 * u + 1]);

        // preload: acc = 1024*h_old + 1024*c0 -> acc_post = 1024*h_new
        f32x4 acc;
        acc[0] = hl[0] * ASCALE + c0s[0];
        acc[1] = hl[1] * ASCALE + c0s[1];
        acc[2] = hl[2] * ASCALE + c0s[2];
        acc[3] = hl[3] * ASCALE + c0s[3];

        FragH f;
        #define MM(C) acc = __builtin_amdgcn_mfma_f32_16x16x32_f16(af[C], f.v, acc, 0, 0, 0);
        // c0: lin 0-3, sin 0-3
        f.p[0] = hp[0]; f.p[1] = hp[1];
        f.p[2] = pkrtz(__sinf(hl[0]), __sinf(hl[1]));
        f.p[3] = pkrtz(__sinf(hl[2]), __sinf(hl[3]));
        MM(0)
        // c1: diag 0-3, within-pair crosses, odd-rep v=1 pkA
        f.p[0] = hp[0] * hp[0]; f.p[1] = hp[1] * hp[1];
        f.p[2] = pkrtz(hl[0] * hl[1], hl[2] * hl[3]);
        f.p[3] = hp[0] * hp[1];
        MM(1)
        // c2
        f.p[0] = hp[0] * SW(hp[1]); f.p[1] = hp[0] * hp[3];
        f.p[2] = hp[0] * SW(hp[3]); f.p[3] = hp[0] * hp[5];
        MM(2)
        // c3
        f.p[0] = hp[0] * SW(hp[5]); f.p[1] = hp[0] * hp[7];
        f.p[2] = hp[0] * SW(hp[7]); f.p[3] = hp[0] * hp[2];
        MM(3)
        // c4
        f.p[0] = hp[0] * SW(hp[2]); f.p[1] = hp[1] * hp[3];
        f.p[2] = hp[1] * SW(hp[3]); f.p[3] = hp[0] * hp[4];
        MM(4)
        // c5
        f.p[0] = hp[0] * SW(hp[4]); f.p[1] = hp[1] * hp[5];
        f.p[2] = hp[1] * SW(hp[5]); f.p[3] = hp[0] * hp[6];
        MM(5)
        // c6
        f.p[0] = hp[0] * SW(hp[6]); f.p[1] = hp[1] * hp[7];
        f.p[2] = hp[1] * SW(hp[7]); f.p[3] = (h2)(_Float16)0;
        MM(6)
        #undef MM

        // scale back (exact pow2), broadcast to all groups via 12 shfl_xor
        float hn0 = acc[0] * INV_ASCALE, hn1 = acc[1] * INV_ASCALE;
        float hn2 = acc[2] * INV_ASCALE, hn3 = acc[3] * INV_ASCALE;
        hl[0] = hn0; hl[1] = hn1; hl[2] = hn2; hl[3] = hn3;
        hl[4]  = __shfl_xor(hn0, 16); hl[5]  = __shfl_xor(hn1, 16);
        hl[6]  = __shfl_xor(hn2, 16); hl[7]  = __shfl_xor(hn3, 16);
        hl[8]  = __shfl_xor(hn0, 32); hl[9]  = __shfl_xor(hn1, 32);
        hl[10] = __shfl_xor(hn2, 32); hl[11] = __shfl_xor(hn3, 32);
        hl[12] = __shfl_xor(hn0, 48); hl[13] = __shfl_xor(hn1, 48);
        hl[14] = __shfl_xor(hn2, 48); hl[15] = __shfl_xor(hn3, 48);
    }

    // ---- store: out[n][r][4g+j] = hl[j] ----
    if (n < N) {
        float* op = out + ((size_t)n * NREP + r) * LATENT + 4 * g;
        *reinterpret_cast<float4*>(op) = make_float4(hl[0], hl[1], hl[2], hl[3]);
    }
}

extern "C" void kernel_launch(void* const* d_in, const int* in_sizes, int n_in,
                              void* d_out, int out_size, void* d_ws, size_t ws_size,
                              hipStream_t stream) {
    const float* h_t   = (const float*)d_in[0];
    const float* coeff = (const float*)d_in[1];
    const float* mask  = (const float*)d_in[2];
    float* out = (float*)d_out;

    const int N = in_sizes[0] / LATENT;          // 50000
    const int ntiles = (N + 15) / 16;            // 3125
    const int nwaves = NREP * ntiles;            // 31250
    const int nblocks = (nwaves + 3) / 4;

    if (ws_size >= (size_t)WS_TOTAL) {
        pack_A16_kernel<<<dim3(NREP), dim3(448), 0, stream>>>(coeff, mask, (char*)d_ws);
        sindy_f16_kernel<true><<<dim3(nblocks), dim3(256), 0, stream>>>(
            h_t, coeff, mask, (const char*)d_ws, out, N, ntiles);
    } else {
        sindy_f16_kernel<false><<<dim3(nblocks), dim3(256), 0, stream>>>(
            h_t, coeff, mask, (const char*)d_ws, out, N, ntiles);
    }
}

// Round 8
// 55.202 us; speedup vs baseline: 4.2138x; 1.1191x over previous
//
#include <hip/hip_runtime.h>
#include <hip/hip_bf16.h>
#include <math.h>

#define LATENT 16
#define NREP 10
#define NSTEPS 10
#define NTERMS 169          // 1 + 16 + 136 + 16
#define NCHUNK 7            // 7 x K=32 = 224 k-slots (168 live + dead pads; ONE folded)
#define DT 0.01f
#define ASCALE 1024.0f      // exact pow2: lifts f16 A-coeffs out of subnormal range
#define INV_ASCALE (1.0f/1024.0f)

#define WS_A_BYTES (NREP * NCHUNK * 64 * 16)     // 71680
#define WS_C0_OFF  WS_A_BYTES
#define WS_TOTAL   (WS_A_BYTES + NREP * LATENT * 4)

typedef _Float16 h2 __attribute__((ext_vector_type(2)));
typedef _Float16 half8 __attribute__((ext_vector_type(8)));
typedef __fp16 fp16x2 __attribute__((ext_vector_type(2)));
typedef __attribute__((ext_vector_type(4))) float f32x4;

union FragH  { half8 v; h2 p[4]; int4 i4; };
union FragHE { half8 v; _Float16 e[8]; int4 i4; };

#define SW(x) __builtin_shufflevector((x), (x), 1, 0)

// v_cvt_pkrtz_f16_f32 with a bit-exact type bridge (__fp16x2 -> _Float16x2)
__device__ __forceinline__ h2 pkrtz(float a, float b) {
    fp16x2 r = __builtin_amdgcn_cvt_pkrtz(a, b);
    return __builtin_bit_cast(h2, r);
}

// shfl_xor on a packed f16 pair (bit-exact through int)
__device__ __forceinline__ h2 shfl_xor_h2(h2 v, int mask) {
    int i = __builtin_bit_cast(int, v);
    return __builtin_bit_cast(h2, __shfl_xor(i, mask));
}

// ---------------- slot -> library row mapping (IDENTICAL to round 7) ----------
// Base program of 56 slots shared by all 4 k-groups g (sigma_g = XOR(4g) on dims,
// = XOR(2g) on pair index u). Lane group g holds the sigma_g-permuted h; running
// the SAME program yields the sigma_g-image term.
// Slots: 0-3 LIN(a=0..3), 4-7 SIN(a=0..3), 8-11 DIAG(a=0..3),
// 12-13 within-pair cross (h0h1, h2h3),
// 14-29 odd-distance pair reps {P0,Pv} v=1,3,5,7 (all groups live),
// 30-53 even-distance pair reps {0,2},{1,3},{0,4},{1,5},{0,6},{1,7} (half dead),
// 54-55 dead pad. ONE (row 0) folded into acc preload.
__host__ __device__ constexpr int quadrow(int x, int y) {
    if (x > y) { int t = x; x = y; y = t; }
    return 17 + x * 16 - x * (x - 1) / 2 + (y - x);     // np.triu_indices order
}

__host__ __device__ constexpr int krow16(int m, int g) {
    const int sh = 4 * g;
    if (m < 4)  return 1 + (m ^ sh);
    if (m < 8)  return 153 + ((m - 4) ^ sh);
    if (m < 12) { const int a = (m - 8) ^ sh; return quadrow(a, a); }
    if (m < 14) { const int u = m - 12; return quadrow((2*u) ^ sh, (2*u+1) ^ sh); }
    if (m < 30) {
        const int idx = m - 14, rep = idx >> 2, w = idx & 3;
        const int v = 2 * rep + 1;
        const int a = ((w == 1 || w == 3) ? 1 : 0);
        const int b = 2 * v + ((w == 1 || w == 2) ? 1 : 0);
        return quadrow(a ^ sh, b ^ sh);
    }
    if (m < 54) {
        const int idx = m - 30, rep = idx >> 2, w = idx & 3;
        const int u = rep & 1;
        const int v = 2 + 2 * (rep >> 1) + (rep & 1);
        const int d = u ^ v;
        const bool live = (d == 2) ? (g == 0 || g == 2) : (g == 0 || g == 1);
        if (!live) return -1;
        const int a = 2 * u + ((w == 1 || w == 3) ? 1 : 0);
        const int b = 2 * v + ((w == 1 || w == 2) ? 1 : 0);
        return quadrow(a ^ sh, b ^ sh);
    }
    return -1;
}

// ---------------- kernel 1: pack A fragments + c0 into ws (unchanged) --------
__global__ __launch_bounds__(448) void pack_A16_kernel(
    const float* __restrict__ coeff, const float* __restrict__ mask, char* __restrict__ ws)
{
    const int r = blockIdx.x;
    const int tid = threadIdx.x;          // 448 = 7 chunks x 64 lanes
    const int c = tid >> 6, lane = tid & 63;
    const int d = lane & 15, g = lane >> 4;
    const float* cr = coeff + (size_t)r * NTERMS * LATENT;
    const float* mr = mask  + (size_t)r * NTERMS * LATENT;
    FragHE a;
    for (int e = 0; e < 8; ++e) {
        const int row = krow16(c * 8 + e, g);
        float v = 0.0f;
        if (row >= 0) v = cr[row * LATENT + d] * mr[row * LATENT + d] * (DT * ASCALE);
        a.e[e] = (_Float16)v;
    }
    reinterpret_cast<int4*>(ws)[((size_t)r * NCHUNK + c) * 64 + lane] = a.i4;

    if (tid < LATENT) {
        float* c0p = reinterpret_cast<float*>(ws + WS_C0_OFF);
        c0p[r * LATENT + tid] = cr[tid] * mr[tid] * (DT * ASCALE);   // library row 0
    }
}

// ---------------- kernel 2: main integration ----------------
// One wave = 16 trajectories x 4 k-groups. col=lane&15, g=lane>>4.
// Each lane keeps ONLY its own 4-dim block (global dims 4g..4g+3) in f32;
// the other 12 h-values circulate as packed f16 pairs via 6 shfl_xor/step.
template<bool USE_WS>
__global__ __launch_bounds__(256, 4) void sindy_f16_kernel(
    const float* __restrict__ h_t,    // [N, 16]
    const float* __restrict__ coeff,  // [10, 169, 16]
    const float* __restrict__ mask,   // [10, 169, 16]
    const char* __restrict__ ws,
    float* __restrict__ out,          // [N, 10, 16]
    int N, int ntiles)
{
    const int lane = threadIdx.x & 63;
    const int wid  = blockIdx.x * 4 + (threadIdx.x >> 6);
    if (wid >= NREP * ntiles) return;
    const int r    = wid / ntiles;
    const int tile = wid % ntiles;

    const int col = lane & 15;        // trajectory within tile; also A dim column
    const int g   = lane >> 4;        // k-group; sigma = XOR(4g)

    // ---- A fragments (28 VGPR, loop-invariant) ----
    half8 af[NCHUNK];
    if constexpr (USE_WS) {
        const int4* wa = reinterpret_cast<const int4*>(ws);
        #pragma unroll
        for (int c = 0; c < NCHUNK; ++c) {
            FragH a; a.i4 = wa[((size_t)r * NCHUNK + c) * 64 + lane];
            af[c] = a.v;
        }
    } else {
        const float* cr = coeff + (size_t)r * NTERMS * LATENT;
        const float* mr = mask  + (size_t)r * NTERMS * LATENT;
        #pragma unroll
        for (int c = 0; c < NCHUNK; ++c) {
            FragHE a;
            #pragma unroll
            for (int e = 0; e < 8; ++e) {
                const int row = krow16(c * 8 + e, g);
                float v = 0.0f;
                if (row >= 0) v = cr[row * LATENT + col] * mr[row * LATENT + col] * (DT * ASCALE);
                a.e[e] = (_Float16)v;
            }
            af[c] = a.v;
        }
    }

    // ---- scaled constant column (ONE term), own dims 4g..4g+3 ----
    float c0s[4];
    if constexpr (USE_WS) {
        const float4 v = *reinterpret_cast<const float4*>(
            ws + WS_C0_OFF + ((size_t)r * LATENT + 4 * g) * 4);
        c0s[0] = v.x; c0s[1] = v.y; c0s[2] = v.z; c0s[3] = v.w;
    } else {
        const float* cr = coeff + (size_t)r * NTERMS * LATENT;
        const float* mr = mask  + (size_t)r * NTERMS * LATENT;
        #pragma unroll
        for (int j = 0; j < 4; ++j) {
            const int d2 = 4 * g + j;
            c0s[j] = cr[d2] * mr[d2] * (DT * ASCALE);
        }
    }

    // ---- own h block only: h[j] = h_global[4g + j] (one float4) ----
    const int n = tile * 16 + col;
    float h0, h1, h3c, h2c;
    {
        float4 q = make_float4(0.f, 0.f, 0.f, 0.f);
        if (n < N)
            q = *reinterpret_cast<const float4*>(h_t + (size_t)n * LATENT + 4 * g);
        h0 = q.x; h1 = q.y; h2c = q.z; h3c = q.w;
    }

    // ---- 10 sequential Euler steps ----
    for (int s = 0; s < NSTEPS; ++s) {
        // own pairs, then broadcast packed pairs across g-groups:
        // hp[2u+t] = pair t of sigma_g-permuted block u  (= own pair of group g^u)
        h2 hp[8];
        hp[0] = pkrtz(h0, h1);
        hp[1] = pkrtz(h2c, h3c);
        #pragma unroll
        for (int u = 1; u < 4; ++u) {
            hp[2 * u]     = shfl_xor_h2(hp[0], 16 * u);
            hp[2 * u + 1] = shfl_xor_h2(hp[1], 16 * u);
        }

        // preload: acc = 1024*h_old + 1024*c0 -> acc_post = 1024*h_new
        f32x4 acc;
        acc[0] = fmaf(h0,  ASCALE, c0s[0]);
        acc[1] = fmaf(h1,  ASCALE, c0s[1]);
        acc[2] = fmaf(h2c, ASCALE, c0s[2]);
        acc[3] = fmaf(h3c, ASCALE, c0s[3]);

        FragH f;
        #define MM(C) acc = __builtin_amdgcn_mfma_f32_16x16x32_f16(af[C], f.v, acc, 0, 0, 0);
        // c0: lin 0-3, sin 0-3 (own block f32)
        f.p[0] = hp[0]; f.p[1] = hp[1];
        f.p[2] = pkrtz(__sinf(h0), __sinf(h1));
        f.p[3] = pkrtz(__sinf(h2c), __sinf(h3c));
        MM(0)
        // c1: diag 0-3, within-pair crosses (own f32), odd-rep v=1 pkA
        f.p[0] = hp[0] * hp[0]; f.p[1] = hp[1] * hp[1];
        f.p[2] = pkrtz(h0 * h1, h2c * h3c);
        f.p[3] = hp[0] * hp[1];
        MM(1)
        // c2
        f.p[0] = hp[0] * SW(hp[1]); f.p[1] = hp[0] * hp[3];
        f.p[2] = hp[0] * SW(hp[3]); f.p[3] = hp[0] * hp[5];
        MM(2)
        // c3
        f.p[0] = hp[0] * SW(hp[5]); f.p[1] = hp[0] * hp[7];
        f.p[2] = hp[0] * SW(hp[7]); f.p[3] = hp[0] * hp[2];
        MM(3)
        // c4
        f.p[0] = hp[0] * SW(hp[2]); f.p[1] = hp[1] * hp[3];
        f.p[2] = hp[1] * SW(hp[3]); f.p[3] = hp[0] * hp[4];
        MM(4)
        // c5
        f.p[0] = hp[0] * SW(hp[4]); f.p[1] = hp[1] * hp[5];
        f.p[2] = hp[1] * SW(hp[5]); f.p[3] = hp[0] * hp[6];
        MM(5)
        // c6
        f.p[0] = hp[0] * SW(hp[6]); f.p[1] = hp[1] * hp[7];
        f.p[2] = hp[1] * SW(hp[7]); f.p[3] = (h2)(_Float16)0;
        MM(6)
        #undef MM

        // scale back (exact pow2): new own h
        h0  = acc[0] * INV_ASCALE;
        h1  = acc[1] * INV_ASCALE;
        h2c = acc[2] * INV_ASCALE;
        h3c = acc[3] * INV_ASCALE;
    }

    // ---- store: out[n][r][4g+j] = own h ----
    if (n < N) {
        float* op = out + ((size_t)n * NREP + r) * LATENT + 4 * g;
        *reinterpret_cast<float4*>(op) = make_float4(h0, h1, h2c, h3c);
    }
}

extern "C" void kernel_launch(void* const* d_in, const int* in_sizes, int n_in,
                              void* d_out, int out_size, void* d_ws, size_t ws_size,
                              hipStream_t stream) {
    const float* h_t   = (const float*)d_in[0];
    const float* coeff = (const float*)d_in[1];
    const float* mask  = (const float*)d_in[2];
    float* out = (float*)d_out;

    const int N = in_sizes[0] / LATENT;          // 50000
    const int ntiles = (N + 15) / 16;            // 3125
    const int nwaves = NREP * ntiles;            // 31250
    const int nblocks = (nwaves + 3) / 4;

    if (ws_size >= (size_t)WS_TOTAL) {
        pack_A16_kernel<<<dim3(NREP), dim3(448), 0, stream>>>(coeff, mask, (char*)d_ws);
        sindy_f16_kernel<true><<<dim3(nblocks), dim3(256), 0, stream>>>(
            h_t, coeff, mask, (const char*)d_ws, out, N, ntiles);
    } else {
        sindy_f16_kernel<false><<<dim3(nblocks), dim3(256), 0, stream>>>(
            h_t, coeff, mask, (const char*)d_ws, out, N, ntiles);
    }
}